// Round 1
// baseline (3944.404 us; speedup 1.0000x reference)
//
#include <hip/hip_runtime.h>
#include <hip/hip_bf16.h>

// MSDNet: only scale 2's chain matters (scales 0,1 are dead code in the
// reference), and final_logits == logits at depth 3. So:
//   f = conv3x3(x, init_w[2], init_b[2])             (no relu)
//   for i in 0..3: f = relu(conv3x3(f, block_w[i,2], block_b[i,2]))
//                  pooled[i] = mean_HW(f)
//   per sample: chosen = first i in {0,1,2} with maxsoftmax(logits_i)>=0.9 else 3
//   out = logits[chosen]

#define Hdim 112
#define Wdim 112
#define NB   16
#define CCH  128
#define NCLS 100

// ---------------- direct 3x3 conv, SAME padding, NCHW ----------------
// Block: 16x16 spatial tile x 32 output channels. 256 threads.
// Thread: 2x2 spatial x 8 couts register tile.
template<int CIN>
__global__ __launch_bounds__(256) void conv3x3(
    const float* __restrict__ in,    // [NB][CIN][H][W]
    const float* __restrict__ wgt,   // [128][CIN][3][3]
    const float* __restrict__ bias,  // [128]
    float* __restrict__ out,         // [NB][128][H][W]
    int do_relu)
{
    constexpr int CK = (CIN < 16) ? CIN : 16;
    constexpr int CO = 32;

    const int tile = blockIdx.x;          // 0..48
    const int cg   = blockIdx.y;          // 0..3
    const int n    = blockIdx.z;          // 0..15
    const int h0 = (tile / 7) * 16;
    const int w0 = (tile % 7) * 16;
    const int tid = threadIdx.x;
    const int sid = tid & 63;
    const int wv  = tid >> 6;             // 0..3 -> which 8 couts of the 32
    const int tx  = sid & 7;              // 0..7
    const int ty  = sid >> 3;             // 0..7

    __shared__ float s_in[CK][18][18];
    __shared__ float s_w[CK][9][CO];      // [cin][kh*3+kw][cout]

    float acc[2][2][8];
    #pragma unroll
    for (int a = 0; a < 2; a++)
        #pragma unroll
        for (int b = 0; b < 2; b++)
            #pragma unroll
            for (int c = 0; c < 8; c++) acc[a][b][c] = 0.f;

    const float* in_n = in + (size_t)n * CIN * Hdim * Wdim;
    const int cbase = cg * CO;

    for (int c0 = 0; c0 < CIN; c0 += CK) {
        __syncthreads();
        // stage input halo tile: CK x 18 x 18 (zero-padded)
        for (int e = tid; e < CK * 324; e += 256) {
            int ckl = e / 324, p = e % 324;
            int y = p / 18, x = p % 18;
            int gh = h0 + y - 1, gw = w0 + x - 1;
            float v = 0.f;
            if ((unsigned)gh < Hdim && (unsigned)gw < Wdim)
                v = in_n[(size_t)(c0 + ckl) * Hdim * Wdim + gh * Wdim + gw];
            s_in[ckl][y][x] = v;
        }
        // stage weights: wgt[cbase+co][c0+ck][kidx] -> s_w[ck][kidx][co]
        for (int e = tid; e < CK * 9 * CO; e += 256) {
            int co = e / (CK * 9), r = e % (CK * 9);
            int ckl = r / 9, kidx = r % 9;
            s_w[ckl][kidx][co] =
                wgt[((size_t)(cbase + co) * CIN + c0 + ckl) * 9 + kidx];
        }
        __syncthreads();

        #pragma unroll 4
        for (int ck = 0; ck < CK; ck++) {
            float rowv[4][4];
            #pragma unroll
            for (int r = 0; r < 4; r++) {
                float2 a  = *(const float2*)&s_in[ck][ty * 2 + r][tx * 2];
                float2 b2 = *(const float2*)&s_in[ck][ty * 2 + r][tx * 2 + 2];
                rowv[r][0] = a.x; rowv[r][1] = a.y;
                rowv[r][2] = b2.x; rowv[r][3] = b2.y;
            }
            #pragma unroll
            for (int kh = 0; kh < 3; kh++) {
                #pragma unroll
                for (int kw = 0; kw < 3; kw++) {
                    float i00 = rowv[kh][kw];
                    float i01 = rowv[kh][kw + 1];
                    float i10 = rowv[kh + 1][kw];
                    float i11 = rowv[kh + 1][kw + 1];
                    const float* wp = &s_w[ck][kh * 3 + kw][wv * 8];
                    #pragma unroll
                    for (int co = 0; co < 8; co++) {
                        float wval = wp[co];
                        acc[0][0][co] += i00 * wval;
                        acc[0][1][co] += i01 * wval;
                        acc[1][0][co] += i10 * wval;
                        acc[1][1][co] += i11 * wval;
                    }
                }
            }
        }
    }

    // epilogue: bias (+relu), store
    #pragma unroll
    for (int co = 0; co < 8; co++) {
        int c = cbase + wv * 8 + co;
        float bv = bias[c];
        #pragma unroll
        for (int dy = 0; dy < 2; dy++) {
            #pragma unroll
            for (int dx = 0; dx < 2; dx++) {
                float v = acc[dy][dx][co] + bv;
                if (do_relu) v = fmaxf(v, 0.f);
                out[((size_t)n * CCH + c) * Hdim * Wdim +
                    (size_t)(h0 + ty * 2 + dy) * Wdim + (w0 + tx * 2 + dx)] = v;
            }
        }
    }
}

// ---------------- global average pool over HxW per (n,c) plane ----------------
__global__ __launch_bounds__(256) void pool_mean(
    const float* __restrict__ f, float* __restrict__ pooled)
{
    int nc = blockIdx.x;                  // n*128 + c, 2048 blocks
    const float* p = f + (size_t)nc * (Hdim * Wdim);
    float s = 0.f;
    for (int i = threadIdx.x; i < Hdim * Wdim; i += 256) s += p[i];
    #pragma unroll
    for (int o = 32; o > 0; o >>= 1) s += __shfl_down(s, o, 64);
    __shared__ float wsum[4];
    if ((threadIdx.x & 63) == 0) wsum[threadIdx.x >> 6] = s;
    __syncthreads();
    if (threadIdx.x == 0)
        pooled[nc] = (wsum[0] + wsum[1] + wsum[2] + wsum[3]) * (1.f / (Hdim * Wdim));
}

// ---------------- classifiers + early-exit selection ----------------
__global__ __launch_bounds__(256) void classify(
    const float* __restrict__ pooled,   // [4][16][128]
    const float* __restrict__ cw,       // [4][100][128]
    const float* __restrict__ cb,       // [4][100]
    float* __restrict__ out)            // [16][100]
{
    __shared__ float lg[4][NB][NCLS];
    __shared__ int chosen[NB];
    int tid = threadIdx.x;
    for (int i = 0; i < 4; i++) {
        for (int e = tid; e < NB * NCLS; e += 256) {
            int n = e / NCLS, j = e % NCLS;
            const float* pv = pooled + ((size_t)i * NB + n) * CCH;
            const float* wp = cw + ((size_t)i * NCLS + j) * CCH;
            float s = cb[i * NCLS + j];
            #pragma unroll 8
            for (int c = 0; c < CCH; c++) s += pv[c] * wp[c];
            lg[i][n][j] = s;
        }
    }
    __syncthreads();
    if (tid < NB) {
        int n = tid, ch = 3;
        for (int i = 0; i < 3; i++) {
            float m = -1e30f;
            for (int j = 0; j < NCLS; j++) m = fmaxf(m, lg[i][n][j]);
            float se = 0.f;
            for (int j = 0; j < NCLS; j++) se += expf(lg[i][n][j] - m);
            if (1.f / se >= 0.9f) { ch = i; break; }
        }
        chosen[n] = ch;
    }
    __syncthreads();
    for (int e = tid; e < NB * NCLS; e += 256) {
        int n = e / NCLS, j = e % NCLS;
        out[e] = lg[chosen[n]][n][j];
    }
}

extern "C" void kernel_launch(void* const* d_in, const int* in_sizes, int n_in,
                              void* d_out, int out_size, void* d_ws, size_t ws_size,
                              hipStream_t stream) {
    const float* x       = (const float*)d_in[0];   // [16,3,112,112]
    const float* init_w  = (const float*)d_in[1];   // [3,128,3,3,3]
    const float* init_b  = (const float*)d_in[2];   // [3,128]
    const float* block_w = (const float*)d_in[3];   // [4,3,128,128,3,3]
    const float* block_b = (const float*)d_in[4];   // [4,3,128]
    const float* cls_w   = (const float*)d_in[5];   // [4,100,128]
    const float* cls_b   = (const float*)d_in[6];   // [4,100]
    float* out = (float*)d_out;

    size_t featElems = (size_t)NB * CCH * Hdim * Wdim;  // 25.69M floats
    float* fA = (float*)d_ws;
    float* fB = fA + featElems;
    float* pooled = fB + featElems;                     // [4][16][128]

    dim3 grid(49, 4, NB), blk(256);

    // init conv, scale 2 slice (no relu)
    conv3x3<3><<<grid, blk, 0, stream>>>(
        x, init_w + (size_t)2 * CCH * 3 * 9, init_b + 2 * CCH, fA, 0);

    for (int i = 0; i < 4; i++) {
        conv3x3<128><<<grid, blk, 0, stream>>>(
            fA,
            block_w + ((size_t)i * 3 + 2) * CCH * CCH * 9,
            block_b + ((size_t)i * 3 + 2) * CCH,
            fB, 1);
        pool_mean<<<2048, blk, 0, stream>>>(fB, pooled + (size_t)i * NB * CCH);
        float* t = fA; fA = fB; fB = t;
    }

    classify<<<1, blk, 0, stream>>>(pooled, cls_w, cls_b, out);
}

// Round 2
// 564.607 us; speedup vs baseline: 6.9861x; 6.9861x over previous
//
#include <hip/hip_runtime.h>
#include <hip/hip_bf16.h>

// MSDNet on MI355X. Only scale 2's chain matters (scales 0/1 are dead code),
// and final_logits == logits at depth 3.
// Pipeline:
//   conv_init (fp32 VALU, cin=3) -> bf16 NHWC feats
//   4x { conv_mfma (bf16 MFMA implicit GEMM, 128->128) ; pool_partial }
//   reduce_pool ; classify (early-exit select)

typedef unsigned int uint;
typedef unsigned short u16;
typedef __bf16 bf16x8 __attribute__((ext_vector_type(8)));
typedef short short8 __attribute__((ext_vector_type(8)));
typedef unsigned short ushort8 __attribute__((ext_vector_type(8)));
typedef float f32x4 __attribute__((ext_vector_type(4)));

#define NB   16
#define CCH  128
#define NCLS 100
#define HW   12544      // 112*112

__device__ __forceinline__ u16 f2bf(float f) {
    uint u = __float_as_uint(f);
    return (u16)((u + 0x7fffu + ((u >> 16) & 1u)) >> 16);
}

// ---------------- weight transpose+convert: block_w[d][2][co][ci][kh][kw] f32
// -> wb[d][tap][co][ci] bf16 ----------------
__global__ __launch_bounds__(256) void convert_w(
    const float* __restrict__ bw, u16* __restrict__ wb)
{
    int idx = blockIdx.x * 256 + threadIdx.x;        // 4*9*128*128
    if (idx >= 4 * 9 * 16384) return;
    int d = idx / 147456, r = idx % 147456;
    int t = r / 16384, r2 = r & 16383;
    int co = r2 >> 7, ci = r2 & 127;
    float v = bw[((size_t)(d * 3 + 2) * 16384 + co * 128 + ci) * 9 + t];
    wb[idx] = f2bf(v);
}

// ---------------- init conv: cin=3, fp32 VALU, NCHW fp32 in -> NHWC bf16 out ----------------
__global__ __launch_bounds__(256) void conv_init(
    const float* __restrict__ in,    // [16][3][112][112]
    const float* __restrict__ wgt,   // [128][3][3][3]
    const float* __restrict__ bias,  // [128]
    u16* __restrict__ outp)          // [16][12544][128] bf16
{
    const int tile = blockIdx.x;          // 0..48 (16x16 tiles)
    const int cg   = blockIdx.y;          // 0..3  (32 couts)
    const int n    = blockIdx.z;
    const int h0 = (tile / 7) * 16, w0 = (tile % 7) * 16;
    const int tid = threadIdx.x;
    const int sid = tid & 63, wv = tid >> 6;
    const int tx = sid & 7, ty = sid >> 3;

    __shared__ float s_in[3][18][18];
    __shared__ float s_w[3][9][32];

    float acc[2][2][8];
    #pragma unroll
    for (int a = 0; a < 2; a++)
        #pragma unroll
        for (int b = 0; b < 2; b++)
            #pragma unroll
            for (int c = 0; c < 8; c++) acc[a][b][c] = 0.f;

    const float* in_n = in + (size_t)n * 3 * HW;
    const int cbase = cg * 32;

    for (int e = tid; e < 3 * 324; e += 256) {
        int ck = e / 324, p = e % 324;
        int y = p / 18, x = p % 18;
        int gh = h0 + y - 1, gw = w0 + x - 1;
        float v = 0.f;
        if ((unsigned)gh < 112u && (unsigned)gw < 112u)
            v = in_n[(size_t)ck * HW + gh * 112 + gw];
        s_in[ck][y][x] = v;
    }
    for (int e = tid; e < 3 * 9 * 32; e += 256) {
        int co = e / 27, r = e % 27;
        int ck = r / 9, kidx = r % 9;
        s_w[ck][kidx][co] = wgt[((size_t)(cbase + co) * 3 + ck) * 9 + kidx];
    }
    __syncthreads();

    #pragma unroll
    for (int ck = 0; ck < 3; ck++) {
        float rowv[4][4];
        #pragma unroll
        for (int r = 0; r < 4; r++) {
            float2 a  = *(const float2*)&s_in[ck][ty * 2 + r][tx * 2];
            float2 b2 = *(const float2*)&s_in[ck][ty * 2 + r][tx * 2 + 2];
            rowv[r][0] = a.x; rowv[r][1] = a.y;
            rowv[r][2] = b2.x; rowv[r][3] = b2.y;
        }
        #pragma unroll
        for (int kh = 0; kh < 3; kh++)
            #pragma unroll
            for (int kw = 0; kw < 3; kw++) {
                float i00 = rowv[kh][kw],     i01 = rowv[kh][kw + 1];
                float i10 = rowv[kh + 1][kw], i11 = rowv[kh + 1][kw + 1];
                const float* wp = &s_w[ck][kh * 3 + kw][wv * 8];
                #pragma unroll
                for (int co = 0; co < 8; co++) {
                    float wval = wp[co];
                    acc[0][0][co] += i00 * wval;
                    acc[0][1][co] += i01 * wval;
                    acc[1][0][co] += i10 * wval;
                    acc[1][1][co] += i11 * wval;
                }
            }
    }

    float bv[8];
    #pragma unroll
    for (int co = 0; co < 8; co++) bv[co] = bias[cbase + wv * 8 + co];
    #pragma unroll
    for (int dy = 0; dy < 2; dy++)
        #pragma unroll
        for (int dx = 0; dx < 2; dx++) {
            ushort8 pk;
            #pragma unroll
            for (int co = 0; co < 8; co++)
                pk[co] = f2bf(acc[dy][dx][co] + bv[co]);   // no relu on init
            int h = h0 + ty * 2 + dy, w = w0 + tx * 2 + dx;
            *(ushort8*)(outp + (((size_t)n * HW + h * 112 + w) << 7) + cbase + wv * 8) = pk;
        }
}

// ---------------- MFMA implicit-GEMM 3x3 conv, 128->128, bf16 NHWC ----------------
// Block: 256 thr (4 waves), tile M=128 pixels (8 rows x 16 cols), N=128 couts.
// Wave: 64x64. K-loop: 36 steps (tap-major, 4 cin-chunks of 32).
#define IN_S 136        // LDS elems per pixel (128 + 8 pad) -> 272B stride, 16B-aligned
#define W_S  40         // LDS elems per cout (32 + 8 pad)   -> 80B stride, 16B-aligned

__global__ __launch_bounds__(256, 2) void conv_mfma(
    const u16* __restrict__ in,     // [16][12544][128] bf16
    const u16* __restrict__ wb,     // [9][128][128] bf16 (tap, cout, cin)
    const float* __restrict__ bias, // [128]
    u16* __restrict__ outp)         // [16][12544][128] bf16
{
    __shared__ u16 s_in[180 * IN_S];        // 48,960 B
    __shared__ u16 s_w[2 * 128 * W_S];      // 20,480 B

    const int tile = blockIdx.x;            // 0..97 : (14 h-tiles of 8) x (7 w-tiles of 16)
    const int n    = blockIdx.y;
    const int h0 = (tile / 7) * 8, w0 = (tile % 7) * 16;
    const int tid = threadIdx.x, lane = tid & 63;
    const int wid = tid >> 6, wm = wid >> 1, wn = wid & 1;
    const int l15 = lane & 15, l4 = lane >> 4;

    // ---- stage input patch 10x18 pixels x 128 cin (halo, zero-padded) ----
    const u16* in_n = in + ((size_t)n * HW << 7);
    for (int e = tid; e < 2880; e += 256) {
        int pp = e >> 4, c8 = (e & 15) << 3;
        int hh = pp / 18, ww = pp - hh * 18;
        int gh = h0 + hh - 1, gw = w0 + ww - 1;
        uint4 v = make_uint4(0, 0, 0, 0);
        if ((unsigned)gh < 112u && (unsigned)gw < 112u)
            v = *(const uint4*)(in_n + ((size_t)(gh * 112 + gw) << 7) + c8);
        *(uint4*)(s_in + pp * IN_S + c8) = v;
    }
    // ---- stage weights for step 0 into buf 0 ----
    #pragma unroll
    for (int k = 0; k < 2; ++k) {
        int e = tid + (k << 8);
        int co = e >> 2, ci8 = (e & 3) << 3;
        *(uint4*)(s_w + co * W_S + ci8) = *(const uint4*)(wb + (co << 7) + ci8);
    }

    f32x4 acc[4][4];
    #pragma unroll
    for (int i = 0; i < 4; ++i)
        #pragma unroll
        for (int j = 0; j < 4; ++j)
            #pragma unroll
            for (int e = 0; e < 4; ++e) acc[i][j][e] = 0.f;

    int a_base[4], b_base[4];
    #pragma unroll
    for (int fi = 0; fi < 4; ++fi) a_base[fi] = (wm * 4 + fi) * 18 + l15;
    #pragma unroll
    for (int nj = 0; nj < 4; ++nj) b_base[nj] = (wn * 64 + nj * 16 + l15) * W_S + (l4 << 3);

    #pragma unroll 2
    for (int s = 0; s < 36; ++s) {
        __syncthreads();
        const int cur = s & 1;
        const int t = s >> 2, q = s & 3;
        const int kh = t / 3, kw = t - kh * 3;

        // prefetch next step's weights (global -> regs), written to LDS after MFMAs
        uint4 wreg0, wreg1;
        const int sn = s + 1;
        if (sn < 36) {
            const int t2 = sn >> 2, q2 = sn & 3;
            const u16* wsrc = wb + (t2 << 14) + (q2 << 5);
            int e0 = tid,        co0 = e0 >> 2, k0 = (e0 & 3) << 3;
            int e1 = tid + 256,  co1 = e1 >> 2, k1 = (e1 & 3) << 3;
            wreg0 = *(const uint4*)(wsrc + (co0 << 7) + k0);
            wreg1 = *(const uint4*)(wsrc + (co1 << 7) + k1);
        }

        // fragment reads
        bf16x8 a[4], b[4];
        const int aoff = kh * 18 + kw;
        #pragma unroll
        for (int fi = 0; fi < 4; ++fi) {
            const u16* p = s_in + (a_base[fi] + aoff) * IN_S + (q << 5) + (l4 << 3);
            a[fi] = __builtin_bit_cast(bf16x8, *(const short8*)p);
        }
        const u16* wbuf = s_w + cur * (128 * W_S);
        #pragma unroll
        for (int nj = 0; nj < 4; ++nj)
            b[nj] = __builtin_bit_cast(bf16x8, *(const short8*)(wbuf + b_base[nj]));

        #pragma unroll
        for (int fi = 0; fi < 4; ++fi)
            #pragma unroll
            for (int nj = 0; nj < 4; ++nj)
                acc[fi][nj] = __builtin_amdgcn_mfma_f32_16x16x32_bf16(
                    a[fi], b[nj], acc[fi][nj], 0, 0, 0);

        if (sn < 36) {
            u16* wdst = s_w + (cur ^ 1) * (128 * W_S);
            int e0 = tid,        co0 = e0 >> 2, k0 = (e0 & 3) << 3;
            int e1 = tid + 256,  co1 = e1 >> 2, k1 = (e1 & 3) << 3;
            *(uint4*)(wdst + co0 * W_S + k0) = wreg0;
            *(uint4*)(wdst + co1 * W_S + k1) = wreg1;
        }
    }

    // ---- epilogue: bias + relu, bf16 NHWC stores ----
    // D layout: col = lane&15 (cout), row = l4*4 + reg (pixel-within-16)
    float bv[4];
    #pragma unroll
    for (int nj = 0; nj < 4; ++nj) bv[nj] = bias[wn * 64 + nj * 16 + l15];
    u16* out_n = outp + ((size_t)n * HW << 7);
    #pragma unroll
    for (int fi = 0; fi < 4; ++fi) {
        int h = h0 + wm * 4 + fi;
        #pragma unroll
        for (int j = 0; j < 4; ++j) {
            int w = w0 + (l4 << 2) + j;
            u16* pr = out_n + ((size_t)(h * 112 + w) << 7);
            #pragma unroll
            for (int nj = 0; nj < 4; ++nj) {
                float v = acc[fi][nj][j] + bv[nj];
                pr[wn * 64 + nj * 16 + l15] = f2bf(fmaxf(v, 0.f));
            }
        }
    }
}

// ---------------- pooling: partial sums over pixel slices ----------------
__global__ __launch_bounds__(256) void pool_partial(
    const u16* __restrict__ f,      // [16][12544][128] bf16
    float* __restrict__ partial)    // [16][16][128]  (n, slice, c)
{
    const int n = blockIdx.x, sl = blockIdx.y;
    const int tid = threadIdx.x;
    const int p0 = tid >> 4, c8 = (tid & 15) << 3;
    const u16* base = f + ((size_t)n * HW << 7);
    float s[8];
    #pragma unroll
    for (int j = 0; j < 8; ++j) s[j] = 0.f;
    for (int k = 0; k < 49; ++k) {
        int p = sl * 784 + k * 16 + p0;
        uint4 v = *(const uint4*)(base + ((size_t)p << 7) + c8);
        uint u[4] = {v.x, v.y, v.z, v.w};
        #pragma unroll
        for (int e = 0; e < 4; ++e) {
            s[2 * e]     += __uint_as_float(u[e] << 16);
            s[2 * e + 1] += __uint_as_float(u[e] & 0xffff0000u);
        }
    }
    __shared__ float red[16][128];
    #pragma unroll
    for (int j = 0; j < 8; ++j) red[p0][c8 + j] = s[j];
    __syncthreads();
    if (tid < 128) {
        float t = 0.f;
        #pragma unroll
        for (int r = 0; r < 16; ++r) t += red[r][tid];
        partial[(n * 16 + sl) * 128 + tid] = t;
    }
}

__global__ __launch_bounds__(256) void reduce_pool(
    const float* __restrict__ partial,  // [4][16][16][128]
    float* __restrict__ pooled)         // [4][16][128]
{
    int idx = blockIdx.x * 256 + threadIdx.x;   // 8192
    if (idx >= 4 * NB * CCH) return;
    int i = idx >> 11, n = (idx >> 7) & 15, c = idx & 127;
    float s = 0.f;
    for (int sl = 0; sl < 16; ++sl)
        s += partial[((i * 16 + n) * 16 + sl) * 128 + c];
    pooled[idx] = s * (1.f / HW);
}

// ---------------- classifiers + early-exit selection ----------------
__global__ __launch_bounds__(256) void classify(
    const float* __restrict__ pooled,   // [4][16][128]
    const float* __restrict__ cw,       // [4][100][128]
    const float* __restrict__ cb,       // [4][100]
    float* __restrict__ out)            // [16][100]
{
    __shared__ float lg[4][NB][NCLS];
    __shared__ int chosen[NB];
    int tid = threadIdx.x;
    for (int i = 0; i < 4; i++) {
        for (int e = tid; e < NB * NCLS; e += 256) {
            int n = e / NCLS, j = e % NCLS;
            const float* pv = pooled + ((size_t)i * NB + n) * CCH;
            const float* wp = cw + ((size_t)i * NCLS + j) * CCH;
            float s = cb[i * NCLS + j];
            #pragma unroll 8
            for (int c = 0; c < CCH; c++) s += pv[c] * wp[c];
            lg[i][n][j] = s;
        }
    }
    __syncthreads();
    if (tid < NB) {
        int n = tid, ch = 3;
        for (int i = 0; i < 3; i++) {
            float m = -1e30f;
            for (int j = 0; j < NCLS; j++) m = fmaxf(m, lg[i][n][j]);
            float se = 0.f;
            for (int j = 0; j < NCLS; j++) se += expf(lg[i][n][j] - m);
            if (1.f / se >= 0.9f) { ch = i; break; }
        }
        chosen[n] = ch;
    }
    __syncthreads();
    for (int e = tid; e < NB * NCLS; e += 256) {
        int n = e / NCLS, j = e % NCLS;
        out[e] = lg[chosen[n]][n][j];
    }
}

extern "C" void kernel_launch(void* const* d_in, const int* in_sizes, int n_in,
                              void* d_out, int out_size, void* d_ws, size_t ws_size,
                              hipStream_t stream) {
    const float* x       = (const float*)d_in[0];
    const float* init_w  = (const float*)d_in[1];
    const float* init_b  = (const float*)d_in[2];
    const float* block_w = (const float*)d_in[3];
    const float* block_b = (const float*)d_in[4];
    const float* cls_w   = (const float*)d_in[5];
    const float* cls_b   = (const float*)d_in[6];
    float* out = (float*)d_out;

    char* ws = (char*)d_ws;
    u16* fA      = (u16*)ws;                        // 51,380,224 B
    u16* fB      = (u16*)(ws + 51380224);           // 51,380,224 B
    u16* wb      = (u16*)(ws + 102760448);          //  1,179,648 B
    float* partial = (float*)(ws + 103940096);      //    524,288 B
    float* pooled  = (float*)(ws + 104464384);      //     32,768 B

    convert_w<<<2304, 256, 0, stream>>>(block_w, wb);
    conv_init<<<dim3(49, 4, NB), 256, 0, stream>>>(
        x, init_w + 2 * 128 * 27, init_b + 2 * 128, fA);

    u16* cur = fA;
    u16* nxt = fB;
    for (int i = 0; i < 4; ++i) {
        conv_mfma<<<dim3(98, NB), 256, 0, stream>>>(
            cur, wb + (size_t)i * 147456, block_b + (i * 3 + 2) * 128, nxt);
        pool_partial<<<dim3(NB, 16), 256, 0, stream>>>(
            nxt, partial + (size_t)i * NB * 16 * 128);
        u16* t = cur; cur = nxt; nxt = t;
    }

    reduce_pool<<<32, 256, 0, stream>>>(partial, pooled);
    classify<<<1, 256, 0, stream>>>(pooled, cls_w, cls_b, out);
}

// Round 3
// 407.136 us; speedup vs baseline: 9.6882x; 1.3868x over previous
//
#include <hip/hip_runtime.h>
#include <hip/hip_bf16.h>

// MSDNet on MI355X. Only scale 2's chain matters (scales 0/1 are dead code),
// and final_logits == logits at depth 3.
// Pipeline:
//   conv_init (fp32 VALU, cin=3) -> bf16 NHWC feats
//   4x conv_mfma (bf16 MFMA implicit GEMM, 128->128) with FUSED pooling
//      (per-block f32 partial sums, no extra pass over feats)
//   logits_k (64 blocks: reduce partials + 100x dot128) ; select_k (early-exit)

typedef unsigned int uint;
typedef unsigned short u16;
typedef __bf16 bf16x8 __attribute__((ext_vector_type(8)));
typedef short short8 __attribute__((ext_vector_type(8)));
typedef unsigned short ushort8 __attribute__((ext_vector_type(8)));
typedef float f32x4 __attribute__((ext_vector_type(4)));

#define NB   16
#define CCH  128
#define NCLS 100
#define HW   12544      // 112*112
#define NTILE 98        // 14 h-tiles x 7 w-tiles per image

__device__ __forceinline__ u16 f2bf(float f) {
    uint u = __float_as_uint(f);
    return (u16)((u + 0x7fffu + ((u >> 16) & 1u)) >> 16);
}

// ---------------- weight transpose+convert: block_w[d][2][co][ci][kh][kw] f32
// -> wb[d][tap][co][ci] bf16 ----------------
__global__ __launch_bounds__(256) void convert_w(
    const float* __restrict__ bw, u16* __restrict__ wb)
{
    int idx = blockIdx.x * 256 + threadIdx.x;        // 4*9*128*128
    if (idx >= 4 * 9 * 16384) return;
    int d = idx / 147456, r = idx % 147456;
    int t = r / 16384, r2 = r & 16383;
    int co = r2 >> 7, ci = r2 & 127;
    float v = bw[((size_t)(d * 3 + 2) * 16384 + co * 128 + ci) * 9 + t];
    wb[idx] = f2bf(v);
}

// ---------------- init conv: cin=3, fp32 VALU, NCHW fp32 in -> NHWC bf16 out ----------------
__global__ __launch_bounds__(256) void conv_init(
    const float* __restrict__ in,    // [16][3][112][112]
    const float* __restrict__ wgt,   // [128][3][3][3]
    const float* __restrict__ bias,  // [128]
    u16* __restrict__ outp)          // [16][12544][128] bf16
{
    const int tile = blockIdx.x;          // 0..48 (16x16 tiles)
    const int cg   = blockIdx.y;          // 0..3  (32 couts)
    const int n    = blockIdx.z;
    const int h0 = (tile / 7) * 16, w0 = (tile % 7) * 16;
    const int tid = threadIdx.x;
    const int sid = tid & 63, wv = tid >> 6;
    const int tx = sid & 7, ty = sid >> 3;

    __shared__ float s_in[3][18][18];
    __shared__ float s_w[3][9][32];

    float acc[2][2][8];
    #pragma unroll
    for (int a = 0; a < 2; a++)
        #pragma unroll
        for (int b = 0; b < 2; b++)
            #pragma unroll
            for (int c = 0; c < 8; c++) acc[a][b][c] = 0.f;

    const float* in_n = in + (size_t)n * 3 * HW;
    const int cbase = cg * 32;

    for (int e = tid; e < 3 * 324; e += 256) {
        int ck = e / 324, p = e % 324;
        int y = p / 18, x = p % 18;
        int gh = h0 + y - 1, gw = w0 + x - 1;
        float v = 0.f;
        if ((unsigned)gh < 112u && (unsigned)gw < 112u)
            v = in_n[(size_t)ck * HW + gh * 112 + gw];
        s_in[ck][y][x] = v;
    }
    for (int e = tid; e < 3 * 9 * 32; e += 256) {
        int co = e / 27, r = e % 27;
        int ck = r / 9, kidx = r % 9;
        s_w[ck][kidx][co] = wgt[((size_t)(cbase + co) * 3 + ck) * 9 + kidx];
    }
    __syncthreads();

    #pragma unroll
    for (int ck = 0; ck < 3; ck++) {
        float rowv[4][4];
        #pragma unroll
        for (int r = 0; r < 4; r++) {
            float2 a  = *(const float2*)&s_in[ck][ty * 2 + r][tx * 2];
            float2 b2 = *(const float2*)&s_in[ck][ty * 2 + r][tx * 2 + 2];
            rowv[r][0] = a.x; rowv[r][1] = a.y;
            rowv[r][2] = b2.x; rowv[r][3] = b2.y;
        }
        #pragma unroll
        for (int kh = 0; kh < 3; kh++)
            #pragma unroll
            for (int kw = 0; kw < 3; kw++) {
                float i00 = rowv[kh][kw],     i01 = rowv[kh][kw + 1];
                float i10 = rowv[kh + 1][kw], i11 = rowv[kh + 1][kw + 1];
                const float* wp = &s_w[ck][kh * 3 + kw][wv * 8];
                #pragma unroll
                for (int co = 0; co < 8; co++) {
                    float wval = wp[co];
                    acc[0][0][co] += i00 * wval;
                    acc[0][1][co] += i01 * wval;
                    acc[1][0][co] += i10 * wval;
                    acc[1][1][co] += i11 * wval;
                }
            }
    }

    float bv[8];
    #pragma unroll
    for (int co = 0; co < 8; co++) bv[co] = bias[cbase + wv * 8 + co];
    #pragma unroll
    for (int dy = 0; dy < 2; dy++)
        #pragma unroll
        for (int dx = 0; dx < 2; dx++) {
            ushort8 pk;
            #pragma unroll
            for (int co = 0; co < 8; co++)
                pk[co] = f2bf(acc[dy][dx][co] + bv[co]);   // no relu on init
            int h = h0 + ty * 2 + dy, w = w0 + tx * 2 + dx;
            *(ushort8*)(outp + (((size_t)n * HW + h * 112 + w) << 7) + cbase + wv * 8) = pk;
        }
}

// ---------------- MFMA implicit-GEMM 3x3 conv, 128->128, bf16 NHWC ----------------
// Block: 256 thr (4 waves), tile M=128 pixels (8 rows x 16 cols), N=128 couts.
// Wave: 64x64. K-loop: 36 steps (tap-major, 4 cin-chunks of 32).
// Epilogue additionally writes this block's pooled partial sum (f32, pre-bf16).
#define IN_S 136        // LDS elems per pixel (128 + 8 pad) -> 272B stride, 16B-aligned
#define W_S  40         // LDS elems per cout (32 + 8 pad)   -> 80B stride, 16B-aligned

__global__ __launch_bounds__(256, 2) void conv_mfma(
    const u16* __restrict__ in,     // [16][12544][128] bf16
    const u16* __restrict__ wb,     // [9][128][128] bf16 (tap, cout, cin)
    const float* __restrict__ bias, // [128]
    u16* __restrict__ outp,         // [16][12544][128] bf16
    float* __restrict__ partial)    // [16][98][128] f32 per-block pooled sums
{
    __shared__ u16 s_in[180 * IN_S];        // 48,960 B
    __shared__ u16 s_w[2 * 128 * W_S];      // 20,480 B
    __shared__ float s_pool[2][128];        //  1,024 B

    const int tile = blockIdx.x;            // 0..97
    const int n    = blockIdx.y;
    const int h0 = (tile / 7) * 8, w0 = (tile % 7) * 16;
    const int tid = threadIdx.x, lane = tid & 63;
    const int wid = tid >> 6, wm = wid >> 1, wn = wid & 1;
    const int l15 = lane & 15, l4 = lane >> 4;

    // ---- stage input patch 10x18 pixels x 128 cin (halo, zero-padded) ----
    const u16* in_n = in + ((size_t)n * HW << 7);
    for (int e = tid; e < 2880; e += 256) {
        int pp = e >> 4, c8 = (e & 15) << 3;
        int hh = pp / 18, ww = pp - hh * 18;
        int gh = h0 + hh - 1, gw = w0 + ww - 1;
        uint4 v = make_uint4(0, 0, 0, 0);
        if ((unsigned)gh < 112u && (unsigned)gw < 112u)
            v = *(const uint4*)(in_n + ((size_t)(gh * 112 + gw) << 7) + c8);
        *(uint4*)(s_in + pp * IN_S + c8) = v;
    }
    // ---- stage weights for step 0 into buf 0 ----
    #pragma unroll
    for (int k = 0; k < 2; ++k) {
        int e = tid + (k << 8);
        int co = e >> 2, ci8 = (e & 3) << 3;
        *(uint4*)(s_w + co * W_S + ci8) = *(const uint4*)(wb + (co << 7) + ci8);
    }

    f32x4 acc[4][4];
    #pragma unroll
    for (int i = 0; i < 4; ++i)
        #pragma unroll
        for (int j = 0; j < 4; ++j)
            #pragma unroll
            for (int e = 0; e < 4; ++e) acc[i][j][e] = 0.f;

    int a_base[4], b_base[4];
    #pragma unroll
    for (int fi = 0; fi < 4; ++fi) a_base[fi] = (wm * 4 + fi) * 18 + l15;
    #pragma unroll
    for (int nj = 0; nj < 4; ++nj) b_base[nj] = (wn * 64 + nj * 16 + l15) * W_S + (l4 << 3);

    #pragma unroll 2
    for (int s = 0; s < 36; ++s) {
        __syncthreads();
        const int cur = s & 1;
        const int t = s >> 2, q = s & 3;
        const int kh = t / 3, kw = t - kh * 3;

        // prefetch next step's weights (global -> regs), written to LDS after MFMAs
        uint4 wreg0, wreg1;
        const int sn = s + 1;
        if (sn < 36) {
            const int t2 = sn >> 2, q2 = sn & 3;
            const u16* wsrc = wb + (t2 << 14) + (q2 << 5);
            int e0 = tid,        co0 = e0 >> 2, k0 = (e0 & 3) << 3;
            int e1 = tid + 256,  co1 = e1 >> 2, k1 = (e1 & 3) << 3;
            wreg0 = *(const uint4*)(wsrc + (co0 << 7) + k0);
            wreg1 = *(const uint4*)(wsrc + (co1 << 7) + k1);
        }

        // fragment reads
        bf16x8 a[4], b[4];
        const int aoff = kh * 18 + kw;
        #pragma unroll
        for (int fi = 0; fi < 4; ++fi) {
            const u16* p = s_in + (a_base[fi] + aoff) * IN_S + (q << 5) + (l4 << 3);
            a[fi] = __builtin_bit_cast(bf16x8, *(const short8*)p);
        }
        const u16* wbuf = s_w + cur * (128 * W_S);
        #pragma unroll
        for (int nj = 0; nj < 4; ++nj)
            b[nj] = __builtin_bit_cast(bf16x8, *(const short8*)(wbuf + b_base[nj]));

        #pragma unroll
        for (int fi = 0; fi < 4; ++fi)
            #pragma unroll
            for (int nj = 0; nj < 4; ++nj)
                acc[fi][nj] = __builtin_amdgcn_mfma_f32_16x16x32_bf16(
                    a[fi], b[nj], acc[fi][nj], 0, 0, 0);

        if (sn < 36) {
            u16* wdst = s_w + (cur ^ 1) * (128 * W_S);
            int e0 = tid,        co0 = e0 >> 2, k0 = (e0 & 3) << 3;
            int e1 = tid + 256,  co1 = e1 >> 2, k1 = (e1 & 3) << 3;
            *(uint4*)(wdst + co0 * W_S + k0) = wreg0;
            *(uint4*)(wdst + co1 * W_S + k1) = wreg1;
        }
    }

    // ---- epilogue: bias + relu, bf16 NHWC stores, fused pooling partial ----
    // D layout: col = lane&15 (cout), row = l4*4 + reg (pixel-within-16)
    float bv[4], ps[4];
    #pragma unroll
    for (int nj = 0; nj < 4; ++nj) { bv[nj] = bias[wn * 64 + nj * 16 + l15]; ps[nj] = 0.f; }
    u16* out_n = outp + ((size_t)n * HW << 7);
    #pragma unroll
    for (int fi = 0; fi < 4; ++fi) {
        int h = h0 + wm * 4 + fi;
        #pragma unroll
        for (int j = 0; j < 4; ++j) {
            int w = w0 + (l4 << 2) + j;
            u16* pr = out_n + ((size_t)(h * 112 + w) << 7);
            #pragma unroll
            for (int nj = 0; nj < 4; ++nj) {
                float v = fmaxf(acc[fi][nj][j] + bv[nj], 0.f);
                ps[nj] += v;
                pr[wn * 64 + nj * 16 + l15] = f2bf(v);
            }
        }
    }
    // reduce pooled partial across the 4 l4 groups (same cout)
    #pragma unroll
    for (int nj = 0; nj < 4; ++nj) {
        ps[nj] += __shfl_xor(ps[nj], 16, 64);
        ps[nj] += __shfl_xor(ps[nj], 32, 64);
    }
    if (l4 == 0) {
        #pragma unroll
        for (int nj = 0; nj < 4; ++nj)
            s_pool[wm][wn * 64 + nj * 16 + l15] = ps[nj];
    }
    __syncthreads();
    if (tid < 128)
        partial[((size_t)n * NTILE + tile) * 128 + tid] = s_pool[0][tid] + s_pool[1][tid];
}

// ---------------- per-(depth,sample): reduce partials + 100 dot-128 ----------------
__global__ __launch_bounds__(128) void logits_k(
    const float* __restrict__ partial,  // [4][16][98][128]
    const float* __restrict__ cw,       // [4][100][128]
    const float* __restrict__ cb,       // [4][100]
    float* __restrict__ lg)             // [4][16][100]
{
    const int i = blockIdx.x, n = blockIdx.y;
    const int tid = threadIdx.x;
    __shared__ float pool[128];
    const float* pp = partial + ((size_t)(i * NB + n) * NTILE) * 128;
    float s = 0.f;
    for (int t = 0; t < NTILE; ++t) s += pp[t * 128 + tid];
    pool[tid] = s * (1.f / HW);
    __syncthreads();
    if (tid < NCLS) {
        const float* wp = cw + ((size_t)i * NCLS + tid) * CCH;
        float a = cb[i * NCLS + tid];
        #pragma unroll
        for (int c = 0; c < CCH; c += 4) {
            float4 w4 = *(const float4*)(wp + c);
            a += pool[c] * w4.x + pool[c + 1] * w4.y
               + pool[c + 2] * w4.z + pool[c + 3] * w4.w;
        }
        lg[(i * NB + n) * NCLS + tid] = a;
    }
}

// ---------------- early-exit selection ----------------
__global__ __launch_bounds__(256) void select_k(
    const float* __restrict__ lg,   // [4][16][100]
    float* __restrict__ out)        // [16][100]
{
    __shared__ float slg[4 * NB * NCLS];
    __shared__ int chosen[NB];
    const int tid = threadIdx.x;
    for (int e = tid; e < 4 * NB * NCLS; e += 256) slg[e] = lg[e];
    __syncthreads();
    if (tid < NB) {
        int n = tid, ch = 3;
        for (int i = 0; i < 3; i++) {
            const float* row = &slg[(i * NB + n) * NCLS];
            float m = -1e30f;
            for (int j = 0; j < NCLS; j++) m = fmaxf(m, row[j]);
            float se = 0.f;
            for (int j = 0; j < NCLS; j++) se += expf(row[j] - m);
            if (1.f / se >= 0.9f) { ch = i; break; }
        }
        chosen[n] = ch;
    }
    __syncthreads();
    for (int e = tid; e < NB * NCLS; e += 256) {
        int n = e / NCLS, j = e % NCLS;
        out[e] = slg[(chosen[n] * NB + n) * NCLS + j];
    }
}

extern "C" void kernel_launch(void* const* d_in, const int* in_sizes, int n_in,
                              void* d_out, int out_size, void* d_ws, size_t ws_size,
                              hipStream_t stream) {
    const float* x       = (const float*)d_in[0];
    const float* init_w  = (const float*)d_in[1];
    const float* init_b  = (const float*)d_in[2];
    const float* block_w = (const float*)d_in[3];
    const float* block_b = (const float*)d_in[4];
    const float* cls_w   = (const float*)d_in[5];
    const float* cls_b   = (const float*)d_in[6];
    float* out = (float*)d_out;

    char* ws = (char*)d_ws;
    u16* fA        = (u16*)ws;                      // 51,380,224 B
    u16* fB        = (u16*)(ws + 51380224);         // 51,380,224 B
    u16* wb        = (u16*)(ws + 102760448);        //  1,179,648 B
    float* partial = (float*)(ws + 103940096);      // 4*16*98*128*4 = 3,211,264 B
    float* lgbuf   = (float*)(ws + 107151360);      // 4*16*100*4 = 25,600 B

    convert_w<<<2304, 256, 0, stream>>>(block_w, wb);
    conv_init<<<dim3(49, 4, NB), 256, 0, stream>>>(
        x, init_w + 2 * 128 * 27, init_b + 2 * 128, fA);

    u16* cur = fA;
    u16* nxt = fB;
    for (int i = 0; i < 4; ++i) {
        conv_mfma<<<dim3(NTILE, NB), 256, 0, stream>>>(
            cur, wb + (size_t)i * 147456, block_b + (i * 3 + 2) * 128, nxt,
            partial + (size_t)i * NB * NTILE * 128);
        u16* t = cur; cur = nxt; nxt = t;
    }

    logits_k<<<dim3(4, NB), 128, 0, stream>>>(partial, cls_w, cls_b, lgbuf);
    select_k<<<1, 256, 0, stream>>>(lgbuf, out);
}